// Round 1
// baseline (76.227 us; speedup 1.0000x reference)
//
#include <hip/hip_runtime.h>
#include <hip/hip_bf16.h>

// ---------------------------------------------------------------------------
// Kernel 1: build the fixed 16x16 unitary U from `weights` (L layers of
// per-qubit RY,RZ then CNOT(0,1), CNOT(2,3)). Thread j evolves basis state |j>
// giving column j. Layout in ws: U_real[a*16+b] at [0..255], U_imag at [256..511].
// Wire q maps to bit (3-q) of the flat index (stride 8>>q), matching the
// reference's (n,2,2,2,2) axis order.
// ---------------------------------------------------------------------------
__global__ __launch_bounds__(64) void setup_U_kernel(const float* __restrict__ w,
                                                     int L, float* __restrict__ U)
{
    const int j = threadIdx.x;
    if (j >= 16) return;

    float ar[16], ai[16];
#pragma unroll
    for (int k = 0; k < 16; ++k) { ar[k] = (k == j) ? 1.f : 0.f; ai[k] = 0.f; }

    for (int l = 0; l < L; ++l) {
#pragma unroll
        for (int q = 0; q < 4; ++q) {
            const float thy = w[l * 8 + q * 2 + 0];
            const float thz = w[l * 8 + q * 2 + 1];
            float cy, sy, cz, sz;
            __sincosf(0.5f * thy, &sy, &cy);
            __sincosf(0.5f * thz, &sz, &cz);
            const int st = 8 >> q;
            // RY(thy) on wire q: [[c,-s],[s,c]]
#pragma unroll
            for (int idx = 0; idx < 16; ++idx) {
                if ((idx & st) == 0) {
                    const int i1 = idx + st;
                    const float a0r = ar[idx], a1r = ar[i1];
                    const float a0i = ai[idx], a1i = ai[i1];
                    ar[idx] = cy * a0r - sy * a1r;  ar[i1] = sy * a0r + cy * a1r;
                    ai[idx] = cy * a0i - sy * a1i;  ai[i1] = sy * a0i + cy * a1i;
                }
            }
            // RZ(thz) on wire q: diag(e^{-i thz/2}, e^{+i thz/2})
#pragma unroll
            for (int idx = 0; idx < 16; ++idx) {
                const float r = ar[idx], im = ai[idx];
                if ((idx & st) == 0) {   // * (cz - i sz)
                    ar[idx] = r * cz + im * sz;
                    ai[idx] = im * cz - r * sz;
                } else {                  // * (cz + i sz)
                    ar[idx] = r * cz - im * sz;
                    ai[idx] = im * cz + r * sz;
                }
            }
        }
        // CNOT(control wire0 [mask 8], target wire1 [mask 4])
#pragma unroll
        for (int idx = 0; idx < 16; ++idx) {
            if ((idx & 8) && !(idx & 4)) {
                const int i2 = idx | 4;
                float tr = ar[idx], ti = ai[idx];
                ar[idx] = ar[i2]; ai[idx] = ai[i2];
                ar[i2] = tr;      ai[i2] = ti;
            }
        }
        // CNOT(control wire2 [mask 2], target wire3 [mask 1])
#pragma unroll
        for (int idx = 0; idx < 16; ++idx) {
            if ((idx & 2) && !(idx & 1)) {
                const int i2 = idx | 1;
                float tr = ar[idx], ti = ai[idx];
                ar[idx] = ar[i2]; ai[idx] = ai[i2];
                ar[i2] = tr;      ai[i2] = ti;
            }
        }
    }

#pragma unroll
    for (int a = 0; a < 16; ++a) {
        U[a * 16 + j]       = ar[a];   // row a, column j (real)
        U[256 + a * 16 + j] = ai[a];   // imag
    }
}

// ---------------------------------------------------------------------------
// Kernel 2: fused per-image pipeline. One block per image (2048 blocks, 256 thr).
// Phase A: thread t = patch t (t<196): psi0 from 4 sincos; A = U*psi0 (512 FMA,
//          U reads are uniform -> s_load); z_q from |A|^2 with bit signs -> qf LDS.
// Phase B: GEMV logits[k] = bc[k] + qf . Wc[k,:], shuffle-reduced, then
//          log_softmax by 10 threads.
// ---------------------------------------------------------------------------
__global__ __launch_bounds__(256) void quanv_fused_kernel(
    const float* __restrict__ x, const float* __restrict__ Wc,
    const float* __restrict__ bc, const float* __restrict__ U,
    float* __restrict__ out)
{
    const int b   = blockIdx.x;
    const int tid = threadIdx.x;

    __shared__ float qf[784];
    __shared__ float red[40];
    __shared__ float logits_s[10];

    // ---- Phase A: quantum patch evaluation (uniform CF; >=196 do dummy work)
    {
        const int p  = (tid < 196) ? tid : 0;
        const int pi = p / 14, pj = p % 14;
        const float* xb = x + b * 784 + pi * 56 + pj * 2;
        const float d0 = xb[0], d1 = xb[1], d2 = xb[28], d3 = xb[29];

        float c0, s0, c1, s1, c2, s2, c3, s3;
        __sincosf(0.5f * d0, &s0, &c0);
        __sincosf(0.5f * d1, &s1, &c1);
        __sincosf(0.5f * d2, &s2, &c2);
        __sincosf(0.5f * d3, &s3, &c3);

        // psi0[idx] = prod over wires, idx = b0*8 + b1*4 + b2*2 + b3
        float psi[16];
        {
            const float w0[2] = {c0, s0}, w1[2] = {c1, s1};
            const float w2[2] = {c2, s2}, w3[2] = {c3, s3};
#pragma unroll
            for (int i0 = 0; i0 < 2; ++i0)
#pragma unroll
                for (int i1 = 0; i1 < 2; ++i1) {
                    const float ab = w0[i0] * w1[i1];
#pragma unroll
                    for (int i2 = 0; i2 < 2; ++i2) {
                        const float abc = ab * w2[i2];
#pragma unroll
                        for (int i3 = 0; i3 < 2; ++i3)
                            psi[i0 * 8 + i1 * 4 + i2 * 2 + i3] = abc * w3[i3];
                    }
                }
        }

        // A = U * psi (U complex, psi real); z_q = sum signed |A_a|^2
        float z0 = 0.f, z1 = 0.f, z2 = 0.f, z3 = 0.f;
#pragma unroll
        for (int a = 0; a < 16; ++a) {
            float Ar = 0.f, Ai = 0.f;
#pragma unroll
            for (int k = 0; k < 16; ++k) {
                Ar = fmaf(U[a * 16 + k],       psi[k], Ar);
                Ai = fmaf(U[256 + a * 16 + k], psi[k], Ai);
            }
            const float pr = Ar * Ar + Ai * Ai;
            z0 += (a & 8) ? -pr : pr;
            z1 += (a & 4) ? -pr : pr;
            z2 += (a & 2) ? -pr : pr;
            z3 += (a & 1) ? -pr : pr;
        }

        if (tid < 196) {
            qf[tid * 4 + 0] = z0;
            qf[tid * 4 + 1] = z1;
            qf[tid * 4 + 2] = z2;
            qf[tid * 4 + 3] = z3;
        }
    }
    __syncthreads();

    // ---- Phase B: GEMV (784 -> 10) + log_softmax
    float acc[10];
#pragma unroll
    for (int k = 0; k < 10; ++k) acc[k] = 0.f;

    for (int f = tid; f < 784; f += 256) {
        const float v = qf[f];
#pragma unroll
        for (int k = 0; k < 10; ++k)
            acc[k] = fmaf(v, Wc[k * 784 + f], acc[k]);
    }

    // wave-level reduction (64 lanes)
#pragma unroll
    for (int k = 0; k < 10; ++k) {
#pragma unroll
        for (int off = 32; off > 0; off >>= 1)
            acc[k] += __shfl_down(acc[k], off, 64);
    }
    const int wave = tid >> 6;
    const int lane = tid & 63;
    if (lane == 0) {
#pragma unroll
        for (int k = 0; k < 10; ++k) red[wave * 10 + k] = acc[k];
    }
    __syncthreads();

    if (tid < 10)
        logits_s[tid] = bc[tid] + red[tid] + red[10 + tid] + red[20 + tid] + red[30 + tid];
    __syncthreads();

    if (tid < 10) {
        float m = logits_s[0];
#pragma unroll
        for (int jj = 1; jj < 10; ++jj) m = fmaxf(m, logits_s[jj]);
        float se = 0.f;
#pragma unroll
        for (int jj = 0; jj < 10; ++jj) se += __expf(logits_s[jj] - m);
        out[b * 10 + tid] = logits_s[tid] - m - __logf(se);
    }
}

// ---------------------------------------------------------------------------
extern "C" void kernel_launch(void* const* d_in, const int* in_sizes, int n_in,
                              void* d_out, int out_size, void* d_ws, size_t ws_size,
                              hipStream_t stream)
{
    const float* x  = (const float*)d_in[0];   // (B,1,28,28)
    const float* w  = (const float*)d_in[1];   // (L,4,2)
    const float* Wc = (const float*)d_in[2];   // (10,784)
    const float* bc = (const float*)d_in[3];   // (10,)
    float* out = (float*)d_out;                // (B,10)
    float* U   = (float*)d_ws;                 // 512 floats

    const int L = in_sizes[1] / 8;
    const int B = in_sizes[0] / 784;

    setup_U_kernel<<<1, 64, 0, stream>>>(w, L, U);
    quanv_fused_kernel<<<B, 256, 0, stream>>>(x, Wc, bc, U, out);
}